// Round 11
// baseline (370.449 us; speedup 1.0000x reference)
//
#include <hip/hip_runtime.h>
#include <math.h>

typedef __attribute__((ext_vector_type(8))) short bf16x8;
typedef __attribute__((ext_vector_type(4))) float f32x4;

#define B_TOT 131072
#define NOBS 17
#define NACT 6
#define NM 8
#define HID 256
#define TS 64
#define NT 512
#define NW 8
#define NOUT 13
#define EPS_MARGIN 0.20f   // 10-sigma of score-diff error (bf16 feat+G + single-pass enc2)
#define CAPF 65536

// LDS row strides (elements)
#define AST 264
#define OST 40
#define MUST 52
#define SCST 12

// ---- workspace layout (bytes) ----
#define OFF_FLAGS 64
#define OFF_W1H  (OFF_FLAGS + 4*CAPF)       /* [256][32] bf16 hi */
#define OFF_W1L  (OFF_W1H + 256*32*2)
#define OFF_W2T  (OFF_W1L + 256*32*2)       /* [256][256] bf16, transposed */
#define OFF_V1T  (OFF_W2T + 256*256*2)
#define OFF_V2T  (OFF_V1T + 256*256*2)
#define OFF_HDT  (OFF_V2T + 256*256*2)      /* [64][256]: 48 mu cols | 8 G cols | 8 pad */
#define OFF_G0   (OFF_HDT + 64*256*2)
#define WS_NEED  (OFF_G0 + 64)

__device__ __forceinline__ unsigned short f2bf(float f) {  // RNE
  unsigned int u = __float_as_uint(f);
  u = (u + 0x7fffu + ((u >> 16) & 1u)) >> 16;
  return (unsigned short)u;
}
__device__ __forceinline__ float bf2f(unsigned short h) {
  return __uint_as_float(((unsigned int)h) << 16);
}
__device__ __forceinline__ float tanh_fast2(float x) {
  float e = __expf(2.0f * x);
  float r = __builtin_amdgcn_rcpf(e + 1.0f);
  return 1.0f - 2.0f * r;
}
__device__ __forceinline__ unsigned int pk2(float a, float b) {  // lo16=bf(a), hi16=bf(b)
  unsigned int r;
  asm("v_cvt_pk_bf16_f32 %0, %1, %2" : "=v"(r) : "v"(a), "v"(b));
  return r;
}
__device__ __forceinline__ f32x4 MFMA(bf16x8 a, bf16x8 b, f32x4 c) {
  return __builtin_amdgcn_mfma_f32_16x16x32_bf16(a, b, c, 0, 0, 0);
}

extern "C" __global__ void ppo_zero(int* cnt) {
  if (cnt && threadIdx.x == 0) cnt[0] = 0;
}

// ---------------- prep (FUSED): weight transpose/bf16 + head matrix + g0 ----------------
extern "C" __global__ __launch_bounds__(256)
void ppo_prep(const float* __restrict__ eW1, const float* __restrict__ eW2,
              const float* __restrict__ vW1, const float* __restrict__ vW2,
              const float* __restrict__ muW, const float* __restrict__ cen,
              const float* __restrict__ smean, const float* __restrict__ svar,
              unsigned char* wsb, int* cnt)
{
  if (blockIdx.x == 864) {   // g0 (+ cnt=0 for fallback path compat)
    int m = threadIdx.x >> 5, l = threadIdx.x & 31;
    double acc = 0.0;
    for (int k = l; k < HID; k += 32) {
      double s = 1.0 / sqrt((double)svar[k] + 1e-6);
      double c = (double)cen[m * HID + k];
      acc += c * (2.0 * (double)smean[k] * s + c);
    }
#pragma unroll
    for (int w = 16; w >= 1; w >>= 1) acc += __shfl_xor(acc, w, 32);
    if (l == 0) ((float*)(wsb + OFF_G0))[m] = (float)acc;
    if (threadIdx.x == 0) cnt[0] = 0;
    return;
  }
  int t = blockIdx.x * 256 + threadIdx.x;
  if (t < 65536) {                       // W2T[c][k] = eW2[k][c]
    int c = t >> 8, k = t & 255;
    ((unsigned short*)(wsb + OFF_W2T))[c * 256 + k] = f2bf(eW2[k * 256 + c]);
  } else if (t < 131072) {
    int u = t - 65536; int c = u >> 8, k = u & 255;
    ((unsigned short*)(wsb + OFF_V1T))[c * 256 + k] = f2bf(vW1[k * 256 + c]);
  } else if (t < 196608) {
    int u = t - 131072; int c = u >> 8, k = u & 255;
    ((unsigned short*)(wsb + OFF_V2T))[c * 256 + k] = f2bf(vW2[k * 256 + c]);
  } else if (t < 212992) {               // HDT: mu cols 0-47, G cols 48-55, pad 56-63
    int u = t - 196608; int c = u >> 8, k = u & 255;
    float v = 0.f;
    if (c < 48) { int m = c / 6, a = c - 6 * m; v = muW[(m * 256 + k) * 6 + a]; }
    else if (c < 56) {
      int m = c - 48;
      double s = 1.0 / sqrt((double)svar[k] + 1e-6);
      v = (float)(-2.0 * s * (double)cen[m * 256 + k]);
    }
    ((unsigned short*)(wsb + OFF_HDT))[c * 256 + k] = f2bf(v);
  } else if (t < 221184) {               // W1T hi/lo, K padded 17->32
    int u = t - 212992; int c = u >> 5, k = u & 31;
    float v = (k < NOBS) ? eW1[k * 256 + c] : 0.f;
    unsigned short hi = f2bf(v);
    ((unsigned short*)(wsb + OFF_W1H))[c * 32 + k] = hi;
    ((unsigned short*)(wsb + OFF_W1L))[c * 32 + k] = f2bf(v - bf2f(hi));
  }
}

// ---- K=256 single-pass gemm: A = weights (global, transposed), B = activations (LDS)
template<int CT>
__device__ __forceinline__ void gemm256(const unsigned short* __restrict__ WT,
                                        const unsigned short* act,
                                        int cb, int l15, int h, f32x4 acc[CT][4])
{
#pragma unroll
  for (int kt = 0; kt < 8; ++kt) {
    int kk = kt * 32 + 8 * h;
    bf16x8 a[CT], b[4];
#pragma unroll
    for (int ct = 0; ct < CT; ++ct)
      a[ct] = *(const bf16x8*)(WT + (cb + 16 * ct + l15) * 256 + kk);
#pragma unroll
    for (int nt = 0; nt < 4; ++nt)
      b[nt] = *(const bf16x8*)(act + (16 * nt + l15) * AST + kk);
#pragma unroll
    for (int ct = 0; ct < CT; ++ct)
#pragma unroll
      for (int nt = 0; nt < 4; ++nt)
        acc[ct][nt] = MFMA(a[ct], b[nt], acc[ct][nt]);
  }
}

// epilogue: tanh -> bf16 -> one b64 write per tile
__device__ __forceinline__ void epi_tanh_store(f32x4 acc[2][4], unsigned short* dst,
                                               int cb, int l15, int h)
{
#pragma unroll
  for (int ct = 0; ct < 2; ++ct)
#pragma unroll
    for (int nt = 0; nt < 4; ++nt) {
      float t0 = tanh_fast2(acc[ct][nt][0]);
      float t1 = tanh_fast2(acc[ct][nt][1]);
      float t2 = tanh_fast2(acc[ct][nt][2]);
      float t3 = tanh_fast2(acc[ct][nt][3]);
      uint2 u; u.x = pk2(t0, t1); u.y = pk2(t2, t3);
      *(uint2*)(dst + (16 * nt + l15) * AST + cb + 16 * ct + 4 * h) = u;
    }
}

// ---------------- main fused kernel + in-block fp64 recheck tail ----------------
// launch_bounds(NT,4): VGPR budget <=128, no spill (r8 lesson). No cross-phase hoists
// (r10 lesson: hoisted frags spilled 45 MB through scratch).
extern "C" __global__ __launch_bounds__(NT, 4)
void ppo_mfma(const float* __restrict__ obs,
              const float* __restrict__ eb1, const float* __restrict__ eb2,
              const float* __restrict__ mub, const float* __restrict__ logstd,
              const float* __restrict__ vb1, const float* __restrict__ vb2,
              const float* __restrict__ vW3, const float* __restrict__ vb3,
              const unsigned char* __restrict__ wsb,
              const float* __restrict__ eW1f, const float* __restrict__ eW2f,
              const float* __restrict__ muWf, const float* __restrict__ cenf,
              const float* __restrict__ smeanf, const float* __restrict__ svarf,
              float* __restrict__ out)
{
  __shared__ __attribute__((aligned(16))) unsigned short Hb[TS * AST]; // 33792 B: h, v1; tail: fp64 bufs
  __shared__ unsigned short Fb[TS * AST];   // 33792 B: feat (front aliased by obs staging)
  __shared__ unsigned short MU[TS * MUST];  // 6656 B
  __shared__ float SC[TS * SCST];           // 3072 B
  __shared__ float VP[NW * TS];             // 2048 B
  __shared__ float LS[48];
  __shared__ int FCNT;                      // recheck list
  __shared__ int FLS[64];                   // total ~79.9 KB -> 2 blocks/CU

  const int tid = threadIdx.x, lane = tid & 63, wid = tid >> 6;
  const int l15 = lane & 15, h = lane >> 4;
  const int cb = wid * 32;
  const int s0 = blockIdx.x * TS;

  const unsigned short* W1H = (const unsigned short*)(wsb + OFF_W1H);
  const unsigned short* W1L = (const unsigned short*)(wsb + OFF_W1L);
  const unsigned short* W2T = (const unsigned short*)(wsb + OFF_W2T);
  const unsigned short* V1T = (const unsigned short*)(wsb + OFF_V1T);
  const unsigned short* V2T = (const unsigned short*)(wsb + OFF_V2T);
  const unsigned short* HDT = (const unsigned short*)(wsb + OFF_HDT);
  const float* g0g = (const float*)(wsb + OFF_G0);

  unsigned short* OBH = Fb;                 // [64][40] obs hi (alias; dead before Fb written)
  unsigned short* OBL = Fb + TS * OST;      // [64][40] obs lo

  // ---- stage: obs split hi/lo, zero K-pad, logstd clamp
  for (int t = tid; t < TS * NOBS; t += NT) {
    int s = t / NOBS, k = t - NOBS * s;
    float v = obs[(size_t)s0 * NOBS + t];
    unsigned short hi = f2bf(v);
    OBH[s * OST + k] = hi;
    OBL[s * OST + k] = f2bf(v - bf2f(hi));
  }
  for (int t = tid; t < TS * (32 - NOBS); t += NT) {
    int s = t / (32 - NOBS), k = NOBS + t - (32 - NOBS) * s;
    OBH[s * OST + k] = 0; OBL[s * OST + k] = 0;
  }
  if (tid < 48) LS[tid] = fminf(fmaxf(logstd[tid], -20.f), 2.f);
  __syncthreads();                                      // (1) obs staged

  // ---- enc1: h = tanh(obs @ W1 + b1), K=32, 3-pass split; reads Fb(obs), writes Hb
  {
    f32x4 acc[2][4];
    f32x4 b0 = *(const f32x4*)(eb1 + cb + 4 * h);
    f32x4 b1 = *(const f32x4*)(eb1 + cb + 16 + 4 * h);
#pragma unroll
    for (int nt = 0; nt < 4; ++nt) { acc[0][nt] = b0; acc[1][nt] = b1; }
    bf16x8 aH[2], aL[2], bH[4], bL[4];
#pragma unroll
    for (int ct = 0; ct < 2; ++ct) {
      aH[ct] = *(const bf16x8*)(W1H + (cb + 16 * ct + l15) * 32 + 8 * h);
      aL[ct] = *(const bf16x8*)(W1L + (cb + 16 * ct + l15) * 32 + 8 * h);
    }
#pragma unroll
    for (int nt = 0; nt < 4; ++nt) {
      bH[nt] = *(const bf16x8*)(OBH + (16 * nt + l15) * OST + 8 * h);
      bL[nt] = *(const bf16x8*)(OBL + (16 * nt + l15) * OST + 8 * h);
    }
#pragma unroll
    for (int ct = 0; ct < 2; ++ct)
#pragma unroll
      for (int nt = 0; nt < 4; ++nt) {
        acc[ct][nt] = MFMA(aH[ct], bH[nt], acc[ct][nt]);
        acc[ct][nt] = MFMA(aL[ct], bH[nt], acc[ct][nt]);
        acc[ct][nt] = MFMA(aH[ct], bL[nt], acc[ct][nt]);
      }
    epi_tanh_store(acc, Hb, cb, l15, h);                // Hb disjoint from Fb: no barrier
  }
  __syncthreads();                                      // (2) h visible; obs reads done

  // ---- enc2: feat = tanh(h @ W2 + b2); reads Hb, writes Fb
  {
    f32x4 acc[2][4];
    f32x4 b0 = *(const f32x4*)(eb2 + cb + 4 * h);
    f32x4 b1 = *(const f32x4*)(eb2 + cb + 16 + 4 * h);
#pragma unroll
    for (int nt = 0; nt < 4; ++nt) { acc[0][nt] = b0; acc[1][nt] = b1; }
    gemm256<2>(W2T, Hb, cb, l15, h, acc);
    epi_tanh_store(acc, Fb, cb, l15, h);
  }
  __syncthreads();                                      // (3) feat visible; Hb reads done

  // ---- heads (waves 0-3: read Fb, write MU/SC) + val1 (all waves: read Fb, write Hb)
  if (wid < 4) {
    f32x4 hacc[1][4];
    f32x4 hb;
    if (wid < 3)      hb = *(const f32x4*)(mub + 16 * wid + 4 * h);
    else if (h < 2)   hb = *(const f32x4*)(g0g + 4 * h);
    else              hb = (f32x4){0.f, 0.f, 0.f, 0.f};
#pragma unroll
    for (int nt = 0; nt < 4; ++nt) hacc[0][nt] = hb;
    gemm256<1>(HDT, Fb, 16 * wid, l15, h, hacc);
    if (wid < 3) {
#pragma unroll
      for (int nt = 0; nt < 4; ++nt) {
        uint2 u;
        u.x = pk2(hacc[0][nt][0], hacc[0][nt][1]);
        u.y = pk2(hacc[0][nt][2], hacc[0][nt][3]);
        *(uint2*)(MU + (16 * nt + l15) * MUST + 16 * wid + 4 * h) = u;
      }
    } else if (h < 2) {
#pragma unroll
      for (int nt = 0; nt < 4; ++nt)
        *(f32x4*)(SC + (16 * nt + l15) * SCST + 4 * h) = hacc[0][nt];
    }
  }
  {
    f32x4 acc[2][4];
    f32x4 b0 = *(const f32x4*)(vb1 + cb + 4 * h);
    f32x4 b1 = *(const f32x4*)(vb1 + cb + 16 + 4 * h);
#pragma unroll
    for (int nt = 0; nt < 4; ++nt) { acc[0][nt] = b0; acc[1][nt] = b1; }
    gemm256<2>(V1T, Fb, cb, l15, h, acc);
    epi_tanh_store(acc, Hb, cb, l15, h);                // Hb free since (3)
  }
  __syncthreads();                                      // (4) v1/MU/SC visible

  // ---- val2 + fused v = v2 @ W3 reduction; reads Hb, writes VP
  if (tid == 0) FCNT = 0;                               // ordered by barrier (5)
  {
    f32x4 acc[2][4];
    f32x4 b0 = *(const f32x4*)(vb2 + cb + 4 * h);
    f32x4 b1 = *(const f32x4*)(vb2 + cb + 16 + 4 * h);
#pragma unroll
    for (int nt = 0; nt < 4; ++nt) { acc[0][nt] = b0; acc[1][nt] = b1; }
    gemm256<2>(V2T, Hb, cb, l15, h, acc);
    f32x4 w30 = *(const f32x4*)(vW3 + cb + 4 * h);
    f32x4 w31 = *(const f32x4*)(vW3 + cb + 16 + 4 * h);
#pragma unroll
    for (int nt = 0; nt < 4; ++nt) {
      float v = 0.f;
#pragma unroll
      for (int r = 0; r < 4; ++r) {
        v = fmaf(tanh_fast2(acc[0][nt][r]), w30[r], v);
        v = fmaf(tanh_fast2(acc[1][nt][r]), w31[r], v);
      }
      v += __shfl_xor(v, 16);
      v += __shfl_xor(v, 32);
      if (h == 0) VP[wid * TS + 16 * nt + l15] = v;
    }
  }
  __syncthreads();                                      // (5) VP ready; FCNT=0 visible

  // ---- final: argmin + near-tie list + gather (wave 0; lane = sample)
  if (wid == 0) {
    int s = lane;
    int best = 0;
    float bs = SC[s * SCST], bs2 = 3.4e38f;
#pragma unroll
    for (int m = 1; m < NM; ++m) {
      float sm = SC[s * SCST + m];
      if (sm < bs) { bs2 = bs; bs = sm; best = m; }  // strict <: first min on tie
      else if (sm < bs2) bs2 = sm;
    }
    if ((bs2 - bs) < EPS_MARGIN) {
      int idx = atomicAdd(&FCNT, 1);
      FLS[idx] = s;
    }
    float v = vb3[0];
#pragma unroll
    for (int w = 0; w < NW; ++w) v += VP[w * TS + s];
    float* orow = out + (size_t)(s0 + s) * NOUT;
#pragma unroll
    for (int a = 0; a < NACT; ++a) orow[a] = bf2f(MU[s * MUST + best * NACT + a]);
#pragma unroll
    for (int a = 0; a < NACT; ++a) orow[NACT + a] = LS[best * NACT + a];
    orow[2 * NACT] = v;
  }
  __syncthreads();                                      // (6) FCNT/FLS ready; Hb dead

  // ---- in-block fp64 recheck of flagged samples (verified round-3 math, verbatim) ----
  const int nf = FCNT;
  if (nf == 0) return;
  double* hbuf  = (double*)Hb;            // 2048 B (Hb: 33792 B free after (6))
  double* fbuf  = hbuf + HID;             // 2048 B
  double* d2buf = fbuf + HID;             // 64 B
  double* obsd  = d2buf + NM;             // 136 B
  int*    bestp = (int*)(obsd + NOBS);

  for (int i = 0; i < nf; ++i) {
    const size_t s = (size_t)(s0 + FLS[i]);
    if (tid < NOBS) obsd[tid] = (double)obs[s * NOBS + tid];
    __syncthreads();
    if (tid < HID) {
      double a1 = (double)eb1[tid];
      for (int k = 0; k < NOBS; ++k) a1 = fma(obsd[k], (double)eW1f[k * HID + tid], a1);
      hbuf[tid] = tanh(a1);
    }
    __syncthreads();
    if (tid < HID) {
      double a2 = (double)eb2[tid];
      for (int k = 0; k < HID; ++k) a2 = fma(hbuf[k], (double)eW2f[k * HID + tid], a2);
      fbuf[tid] = tanh(a2);
    }
    __syncthreads();
    if (tid < HID) {
      int g = tid >> 5, l = tid & 31;
      double dot = 0.0, zn = 0.0, cn = 0.0;
      for (int j = 0; j < HID / 32; ++j) {
        int k = l + j * 32;
        double zs = 1.0 / sqrt((double)svarf[k] + 1e-6);
        double zw = (fbuf[k] - (double)smeanf[k]) * zs;
        double ck = (double)cenf[g * HID + k];
        dot = fma(zw, ck, dot);
        zn  = fma(zw, zw, zn);
        cn  = fma(ck, ck, cn);
      }
      for (int m = 16; m >= 1; m >>= 1) {
        dot += __shfl_xor(dot, m, 32);
        zn  += __shfl_xor(zn,  m, 32);
        cn  += __shfl_xor(cn,  m, 32);
      }
      if (l == 0) d2buf[g] = zn - 2.0 * dot + cn;
    }
    __syncthreads();
    if (tid == 0) {
      int b = 0;
      double bsd = d2buf[0];
      for (int m = 1; m < NM; ++m)
        if (d2buf[m] < bsd) { bsd = d2buf[m]; b = m; }
      bestp[0] = b;
    }
    __syncthreads();
    const int b = bestp[0];
    if (tid < NACT) {
      float acc = mub[b * NACT + tid];
      for (int k = 0; k < HID; ++k)
        acc = fmaf((float)fbuf[k], muWf[(b * HID + k) * NACT + tid], acc);
      out[s * NOUT + tid] = acc;
    } else if (tid < 2 * NACT) {
      int a = tid - NACT;
      float ls = logstd[b * NACT + a];
      out[s * NOUT + NACT + a] = fminf(fmaxf(ls, -20.0f), 2.0f);
    }
    __syncthreads();
  }
}

// ---------------- standalone fp64 recheck (fallback path only; verified) ----------------
extern "C" __global__ __launch_bounds__(256, 2)
void ppo_recheck(const float* __restrict__ obs,
                 const float* __restrict__ eW1, const float* __restrict__ eb1,
                 const float* __restrict__ eW2, const float* __restrict__ eb2,
                 const float* __restrict__ muW, const float* __restrict__ mub,
                 const float* __restrict__ logstd,
                 const float* __restrict__ cen, const float* __restrict__ smean,
                 const float* __restrict__ svar,
                 float* __restrict__ out,
                 const int* cnt, const int* flags, int cap)
{
  if (!cnt) return;
  __shared__ double hbuf[HID];
  __shared__ double fbuf[HID];
  __shared__ double d2buf[NM];
  __shared__ double obsd[NOBS];
  __shared__ int bestv;
  const int tid = threadIdx.x;
  const int n = min(cnt[0], cap);

  for (int i = blockIdx.x; i < n; i += gridDim.x) {
    const int s = flags[i];
    if (tid < NOBS) obsd[tid] = (double)obs[(size_t)s * NOBS + tid];
    __syncthreads();
    double a1 = (double)eb1[tid];
    for (int k = 0; k < NOBS; ++k) a1 = fma(obsd[k], (double)eW1[k * HID + tid], a1);
    hbuf[tid] = tanh(a1);
    __syncthreads();
    double a2 = (double)eb2[tid];
    for (int k = 0; k < HID; ++k) a2 = fma(hbuf[k], (double)eW2[k * HID + tid], a2);
    fbuf[tid] = tanh(a2);
    __syncthreads();
    {
      int g = tid >> 5, l = tid & 31;
      double dot = 0.0, zn = 0.0, cn = 0.0;
      for (int j = 0; j < HID / 32; ++j) {
        int k = l + j * 32;
        double zs = 1.0 / sqrt((double)svar[k] + 1e-6);
        double zw = (fbuf[k] - (double)smean[k]) * zs;
        double ck = (double)cen[g * HID + k];
        dot = fma(zw, ck, dot);
        zn  = fma(zw, zw, zn);
        cn  = fma(ck, ck, cn);
      }
      for (int m = 16; m >= 1; m >>= 1) {
        dot += __shfl_xor(dot, m, 32);
        zn  += __shfl_xor(zn,  m, 32);
        cn  += __shfl_xor(cn,  m, 32);
      }
      if (l == 0) d2buf[g] = zn - 2.0 * dot + cn;
    }
    __syncthreads();
    if (tid == 0) {
      int best = 0;
      double bs = d2buf[0];
      for (int m = 1; m < NM; ++m)
        if (d2buf[m] < bs) { bs = d2buf[m]; best = m; }
      bestv = best;
    }
    __syncthreads();
    const int best = bestv;
    if (tid < NACT) {
      float acc = mub[best * NACT + tid];
      for (int k = 0; k < HID; ++k)
        acc = fmaf((float)fbuf[k], muW[(best * HID + k) * NACT + tid], acc);
      out[(size_t)s * NOUT + tid] = acc;
    } else if (tid < 2 * NACT) {
      int a = tid - NACT;
      float ls = logstd[best * NACT + a];
      out[(size_t)s * NOUT + NACT + a] = fminf(fmaxf(ls, -20.0f), 2.0f);
    }
    __syncthreads();
  }
}

// ---------------- fallback (verified round-3 fp32 path; unused when ws is big) ----------------
extern "C" __global__ __launch_bounds__(NT, 4)
void ppo_fp32_fb(const float* __restrict__ obs,
                 const float* __restrict__ eW1, const float* __restrict__ eb1,
                 const float* __restrict__ eW2, const float* __restrict__ eb2,
                 const float* __restrict__ muW, const float* __restrict__ mub,
                 const float* __restrict__ logstd,
                 const float* __restrict__ vW1, const float* __restrict__ vb1,
                 const float* __restrict__ vW2, const float* __restrict__ vb2,
                 const float* __restrict__ vW3, const float* __restrict__ vb3,
                 const float* __restrict__ cen, const float* __restrict__ smean,
                 const float* __restrict__ svar,
                 float* __restrict__ out, int* cnt, int* flags, int cap)
{
  __shared__ float act[HID * TS];
  __shared__ float mubuf[NM * TS * NACT];
  __shared__ float scbuf[NM * TS];
  __shared__ float zsbuf[HID];
  const int tid  = threadIdx.x;
  const int lane = tid & 63;
  const int wid  = tid >> 6;
  const int c0   = wid * 32;
  const int s0   = blockIdx.x * TS;
  float* obs_s = mubuf;
  for (int idx = tid; idx < TS * NOBS; idx += NT) {
    int s = idx / NOBS, i = idx - s * NOBS;
    obs_s[i * TS + s] = obs[s0 * NOBS + idx];
  }
  if (tid < HID) zsbuf[tid] = (float)(1.0 / sqrt((double)svar[tid] + 1e-6));
  __syncthreads();
  {
    float acc[32];
#pragma unroll
    for (int c = 0; c < 32; ++c) acc[c] = eb1[c0 + c];
    float ob[NOBS];
#pragma unroll
    for (int i = 0; i < NOBS; ++i) ob[i] = obs_s[i * TS + lane];
#pragma unroll
    for (int i = 0; i < NOBS; ++i) {
      const float* w = &eW1[i * HID + c0];
#pragma unroll
      for (int c = 0; c < 32; ++c) acc[c] = fmaf(ob[i], w[c], acc[c]);
    }
#pragma unroll
    for (int c = 0; c < 32; ++c) act[(c0 + c) * TS + lane] = tanh_fast2(acc[c]);
  }
  __syncthreads();
  {
    float acc[32];
#pragma unroll
    for (int c = 0; c < 32; ++c) acc[c] = eb2[c0 + c];
#pragma unroll 4
    for (int k = 0; k < HID; ++k) {
      float a = act[k * TS + lane];
      const float* w = &eW2[k * HID + c0];
#pragma unroll
      for (int c = 0; c < 32; ++c) acc[c] = fmaf(a, w[c], acc[c]);
    }
    __syncthreads();
#pragma unroll
    for (int c = 0; c < 32; ++c) act[(c0 + c) * TS + lane] = tanh_fast2(acc[c]);
  }
  __syncthreads();
  {
    double dot = 0.0, zn = 0.0, cn = 0.0;
    float mu[NACT];
#pragma unroll
    for (int a = 0; a < NACT; ++a) mu[a] = mub[wid * NACT + a];
#pragma unroll 2
    for (int k = 0; k < HID; ++k) {
      float f = act[k * TS + lane];
      double zw = ((double)f - (double)smean[k]) * (double)zsbuf[k];
      double ck = (double)cen[wid * HID + k];
      dot = fma(zw, ck, dot); zn = fma(zw, zw, zn); cn = fma(ck, ck, cn);
      const float* w = &muW[(wid * HID + k) * NACT];
#pragma unroll
      for (int a = 0; a < NACT; ++a) mu[a] = fmaf(f, w[a], mu[a]);
    }
    scbuf[wid * TS + lane] = (float)(zn - 2.0 * dot + cn);
#pragma unroll
    for (int a = 0; a < NACT; ++a) mubuf[(wid * TS + lane) * NACT + a] = mu[a];
  }
  {
    float acc[32];
#pragma unroll
    for (int c = 0; c < 32; ++c) acc[c] = vb1[c0 + c];
#pragma unroll 4
    for (int k = 0; k < HID; ++k) {
      float f = act[k * TS + lane];
      const float* w = &vW1[k * HID + c0];
#pragma unroll
      for (int c = 0; c < 32; ++c) acc[c] = fmaf(f, w[c], acc[c]);
    }
    __syncthreads();
#pragma unroll
    for (int c = 0; c < 32; ++c) act[(c0 + c) * TS + lane] = tanh_fast2(acc[c]);
  }
  __syncthreads();
  {
    float acc[32];
#pragma unroll
    for (int c = 0; c < 32; ++c) acc[c] = vb2[c0 + c];
#pragma unroll 4
    for (int k = 0; k < HID; ++k) {
      float f = act[k * TS + lane];
      const float* w = &vW2[k * HID + c0];
#pragma unroll
      for (int c = 0; c < 32; ++c) acc[c] = fmaf(f, w[c], acc[c]);
    }
    __syncthreads();
#pragma unroll
    for (int c = 0; c < 32; ++c) act[(c0 + c) * TS + lane] = tanh_fast2(acc[c]);
  }
  __syncthreads();
  if (wid == 0) {
    int best = 0;
    float bs = scbuf[lane], bs2 = 3.4e38f;
#pragma unroll
    for (int m = 1; m < NM; ++m) {
      float sm = scbuf[m * TS + lane];
      if (sm < bs) { bs2 = bs; bs = sm; best = m; }
      else if (sm < bs2) bs2 = sm;
    }
    if (cnt && (bs2 - bs) < 1e-2f) {
      int idx = atomicAdd(cnt, 1);
      if (idx < cap) flags[idx] = s0 + lane;
    }
    float v = vb3[0];
#pragma unroll 4
    for (int k = 0; k < HID; ++k) v = fmaf(act[k * TS + lane], vW3[k], v);
    float* orow = &out[(size_t)(s0 + lane) * NOUT];
#pragma unroll
    for (int a = 0; a < NACT; ++a) orow[a] = mubuf[(best * TS + lane) * NACT + a];
#pragma unroll
    for (int a = 0; a < NACT; ++a) {
      float ls = logstd[best * NACT + a];
      orow[NACT + a] = fminf(fmaxf(ls, -20.0f), 2.0f);
    }
    orow[2 * NACT] = v;
  }
}

extern "C" void kernel_launch(void* const* d_in, const int* in_sizes, int n_in,
                              void* d_out, int out_size, void* d_ws, size_t ws_size,
                              hipStream_t stream) {
  const float* obs   = (const float*)d_in[0];
  const float* eW1   = (const float*)d_in[1];
  const float* eb1   = (const float*)d_in[2];
  const float* eW2   = (const float*)d_in[3];
  const float* eb2   = (const float*)d_in[4];
  const float* muW   = (const float*)d_in[5];
  const float* mub   = (const float*)d_in[6];
  const float* lstd  = (const float*)d_in[7];
  const float* vW1   = (const float*)d_in[8];
  const float* vb1   = (const float*)d_in[9];
  const float* vW2   = (const float*)d_in[10];
  const float* vb2   = (const float*)d_in[11];
  const float* vW3   = (const float*)d_in[12];
  const float* vb3   = (const float*)d_in[13];
  const float* cen   = (const float*)d_in[14];
  const float* smean = (const float*)d_in[15];
  const float* svar  = (const float*)d_in[16];
  float* out = (float*)d_out;
  unsigned char* wsb = (unsigned char*)d_ws;

  if (ws_size >= (size_t)WS_NEED) {
    int* cnt = (int*)wsb;
    hipLaunchKernelGGL(ppo_prep, dim3(865), dim3(256), 0, stream,
                       eW1, eW2, vW1, vW2, muW, cen, smean, svar, wsb, cnt);
    hipLaunchKernelGGL(ppo_mfma, dim3(B_TOT / TS), dim3(NT), 0, stream,
                       obs, eb1, eb2, mub, lstd, vb1, vb2, vW3, vb3,
                       (const unsigned char*)wsb,
                       eW1, eW2, muW, cen, smean, svar, out);
  } else {
    int* cnt = nullptr; int* flags = nullptr; int cap = 0;
    if (ws_size >= 1024) {
      cnt = (int*)wsb;
      flags = cnt + 16;
      size_t c = (ws_size - 64) / 4;
      cap = (int)(c < (size_t)CAPF ? c : (size_t)CAPF);
    }
    hipLaunchKernelGGL(ppo_zero, dim3(1), dim3(64), 0, stream, cnt);
    hipLaunchKernelGGL(ppo_fp32_fb, dim3(B_TOT / TS), dim3(NT), 0, stream,
                       obs, eW1, eb1, eW2, eb2, muW, mub, lstd,
                       vW1, vb1, vW2, vb2, vW3, vb3, cen, smean, svar, out,
                       cnt, flags, cap);
    hipLaunchKernelGGL(ppo_recheck, dim3(2048), dim3(256), 0, stream,
                       obs, eW1, eb1, eW2, eb2, muW, mub, lstd,
                       cen, smean, svar, out, cnt, flags, cap);
  }
}

// Round 12
// 228.151 us; speedup vs baseline: 1.6237x; 1.6237x over previous
//
#include <hip/hip_runtime.h>
#include <math.h>

typedef __attribute__((ext_vector_type(8))) short bf16x8;
typedef __attribute__((ext_vector_type(4))) float f32x4;

#define B_TOT 131072
#define NOBS 17
#define NACT 6
#define NM 8
#define HID 256
#define TS 64
#define NT 512
#define NW 8
#define NOUT 13
#define EPS_MARGIN 0.20f   // 10-sigma of score-diff error (bf16 feat+G + single-pass enc2)
#define CAPF 65536

// LDS row strides (elements)
#define AST 264
#define OST 40
#define MUST 52
#define SCST 12

// ---- workspace layout (bytes) ----
#define OFF_FLAGS 64
#define OFF_W1H  (OFF_FLAGS + 4*CAPF)       /* [256][32] bf16 hi */
#define OFF_W1L  (OFF_W1H + 256*32*2)
#define OFF_W2T  (OFF_W1L + 256*32*2)       /* [256][256] bf16, transposed */
#define OFF_V1T  (OFF_W2T + 256*256*2)
#define OFF_V2T  (OFF_V1T + 256*256*2)
#define OFF_HDT  (OFF_V2T + 256*256*2)      /* [64][256]: 48 mu cols | 8 G cols | 8 pad */
#define OFF_G0   (OFF_HDT + 64*256*2)
#define WS_NEED  (OFF_G0 + 64)

__device__ __forceinline__ unsigned short f2bf(float f) {  // RNE
  unsigned int u = __float_as_uint(f);
  u = (u + 0x7fffu + ((u >> 16) & 1u)) >> 16;
  return (unsigned short)u;
}
__device__ __forceinline__ float bf2f(unsigned short h) {
  return __uint_as_float(((unsigned int)h) << 16);
}
__device__ __forceinline__ float tanh_fast2(float x) {
  float e = __expf(2.0f * x);
  float r = __builtin_amdgcn_rcpf(e + 1.0f);
  return 1.0f - 2.0f * r;
}
__device__ __forceinline__ unsigned int pk2(float a, float b) {  // lo16=bf(a), hi16=bf(b)
  unsigned int r;
  asm("v_cvt_pk_bf16_f32 %0, %1, %2" : "=v"(r) : "v"(a), "v"(b));
  return r;
}
__device__ __forceinline__ f32x4 MFMA(bf16x8 a, bf16x8 b, f32x4 c) {
  return __builtin_amdgcn_mfma_f32_16x16x32_bf16(a, b, c, 0, 0, 0);
}

extern "C" __global__ void ppo_zero(int* cnt) {
  if (cnt && threadIdx.x == 0) cnt[0] = 0;
}

// ---------------- prep (FUSED): weight transpose/bf16 + head matrix + g0 + cnt=0 ----------------
extern "C" __global__ __launch_bounds__(256)
void ppo_prep(const float* __restrict__ eW1, const float* __restrict__ eW2,
              const float* __restrict__ vW1, const float* __restrict__ vW2,
              const float* __restrict__ muW, const float* __restrict__ cen,
              const float* __restrict__ smean, const float* __restrict__ svar,
              unsigned char* wsb, int* cnt)
{
  if (blockIdx.x == 864) {   // g0 + cnt=0
    int m = threadIdx.x >> 5, l = threadIdx.x & 31;
    double acc = 0.0;
    for (int k = l; k < HID; k += 32) {
      double s = 1.0 / sqrt((double)svar[k] + 1e-6);
      double c = (double)cen[m * HID + k];
      acc += c * (2.0 * (double)smean[k] * s + c);
    }
#pragma unroll
    for (int w = 16; w >= 1; w >>= 1) acc += __shfl_xor(acc, w, 32);
    if (l == 0) ((float*)(wsb + OFF_G0))[m] = (float)acc;
    if (threadIdx.x == 0) cnt[0] = 0;
    return;
  }
  int t = blockIdx.x * 256 + threadIdx.x;
  if (t < 65536) {                       // W2T[c][k] = eW2[k][c]
    int c = t >> 8, k = t & 255;
    ((unsigned short*)(wsb + OFF_W2T))[c * 256 + k] = f2bf(eW2[k * 256 + c]);
  } else if (t < 131072) {
    int u = t - 65536; int c = u >> 8, k = u & 255;
    ((unsigned short*)(wsb + OFF_V1T))[c * 256 + k] = f2bf(vW1[k * 256 + c]);
  } else if (t < 196608) {
    int u = t - 131072; int c = u >> 8, k = u & 255;
    ((unsigned short*)(wsb + OFF_V2T))[c * 256 + k] = f2bf(vW2[k * 256 + c]);
  } else if (t < 212992) {               // HDT: mu cols 0-47, G cols 48-55, pad 56-63
    int u = t - 196608; int c = u >> 8, k = u & 255;
    float v = 0.f;
    if (c < 48) { int m = c / 6, a = c - 6 * m; v = muW[(m * 256 + k) * 6 + a]; }
    else if (c < 56) {
      int m = c - 48;
      double s = 1.0 / sqrt((double)svar[k] + 1e-6);
      v = (float)(-2.0 * s * (double)cen[m * 256 + k]);
    }
    ((unsigned short*)(wsb + OFF_HDT))[c * 256 + k] = f2bf(v);
  } else if (t < 221184) {               // W1T hi/lo, K padded 17->32
    int u = t - 212992; int c = u >> 5, k = u & 31;
    float v = (k < NOBS) ? eW1[k * 256 + c] : 0.f;
    unsigned short hi = f2bf(v);
    ((unsigned short*)(wsb + OFF_W1H))[c * 32 + k] = hi;
    ((unsigned short*)(wsb + OFF_W1L))[c * 32 + k] = f2bf(v - bf2f(hi));
  }
}

// ---- K=256 single-pass gemm: A = weights (global, transposed), B = activations (LDS)
template<int CT>
__device__ __forceinline__ void gemm256(const unsigned short* __restrict__ WT,
                                        const unsigned short* act,
                                        int cb, int l15, int h, f32x4 acc[CT][4])
{
#pragma unroll
  for (int kt = 0; kt < 8; ++kt) {
    int kk = kt * 32 + 8 * h;
    bf16x8 a[CT], b[4];
#pragma unroll
    for (int ct = 0; ct < CT; ++ct)
      a[ct] = *(const bf16x8*)(WT + (cb + 16 * ct + l15) * 256 + kk);
#pragma unroll
    for (int nt = 0; nt < 4; ++nt)
      b[nt] = *(const bf16x8*)(act + (16 * nt + l15) * AST + kk);
#pragma unroll
    for (int ct = 0; ct < CT; ++ct)
#pragma unroll
      for (int nt = 0; nt < 4; ++nt)
        acc[ct][nt] = MFMA(a[ct], b[nt], acc[ct][nt]);
  }
}

// epilogue: tanh -> bf16 -> one b64 write per tile
__device__ __forceinline__ void epi_tanh_store(f32x4 acc[2][4], unsigned short* dst,
                                               int cb, int l15, int h)
{
#pragma unroll
  for (int ct = 0; ct < 2; ++ct)
#pragma unroll
    for (int nt = 0; nt < 4; ++nt) {
      float t0 = tanh_fast2(acc[ct][nt][0]);
      float t1 = tanh_fast2(acc[ct][nt][1]);
      float t2 = tanh_fast2(acc[ct][nt][2]);
      float t3 = tanh_fast2(acc[ct][nt][3]);
      uint2 u; u.x = pk2(t0, t1); u.y = pk2(t2, t3);
      *(uint2*)(dst + (16 * nt + l15) * AST + cb + 16 * ct + 4 * h) = u;
    }
}

// ---------------- main fused kernel: ROUND-6 BYTE-EXACT (proven 135 us, no spill) ----------------
// Do NOT graft onto this kernel: r8 launch_bounds(,6) -> 432 MB spill; r10 cross-phase
// fragment hoist -> 45 MB spill; r11 in-kernel fp64 tail -> whole-kernel codegen collapse.
extern "C" __global__ __launch_bounds__(NT, 4)
void ppo_mfma(const float* __restrict__ obs,
              const float* __restrict__ eb1, const float* __restrict__ eb2,
              const float* __restrict__ mub, const float* __restrict__ logstd,
              const float* __restrict__ vb1, const float* __restrict__ vb2,
              const float* __restrict__ vW3, const float* __restrict__ vb3,
              const unsigned char* __restrict__ wsb,
              float* __restrict__ out, int* cnt, int* flags, int cap)
{
  __shared__ unsigned short Hb[TS * AST];   // 33792 B: h, then v1
  __shared__ unsigned short Fb[TS * AST];   // 33792 B: feat (front aliased by obs staging)
  __shared__ unsigned short MU[TS * MUST];  // 6656 B
  __shared__ float SC[TS * SCST];           // 3072 B
  __shared__ float VP[NW * TS];             // 2048 B
  __shared__ float LS[48];                  // total 79552 B -> 2 blocks/CU

  const int tid = threadIdx.x, lane = tid & 63, wid = tid >> 6;
  const int l15 = lane & 15, h = lane >> 4;
  const int cb = wid * 32;
  const int s0 = blockIdx.x * TS;

  const unsigned short* W1H = (const unsigned short*)(wsb + OFF_W1H);
  const unsigned short* W1L = (const unsigned short*)(wsb + OFF_W1L);
  const unsigned short* W2T = (const unsigned short*)(wsb + OFF_W2T);
  const unsigned short* V1T = (const unsigned short*)(wsb + OFF_V1T);
  const unsigned short* V2T = (const unsigned short*)(wsb + OFF_V2T);
  const unsigned short* HDT = (const unsigned short*)(wsb + OFF_HDT);
  const float* g0g = (const float*)(wsb + OFF_G0);

  unsigned short* OBH = Fb;                 // [64][40] obs hi (alias; dead before Fb written)
  unsigned short* OBL = Fb + TS * OST;      // [64][40] obs lo

  // ---- stage: obs split hi/lo, zero K-pad, logstd clamp
  for (int t = tid; t < TS * NOBS; t += NT) {
    int s = t / NOBS, k = t - NOBS * s;
    float v = obs[(size_t)s0 * NOBS + t];
    unsigned short hi = f2bf(v);
    OBH[s * OST + k] = hi;
    OBL[s * OST + k] = f2bf(v - bf2f(hi));
  }
  for (int t = tid; t < TS * (32 - NOBS); t += NT) {
    int s = t / (32 - NOBS), k = NOBS + t - (32 - NOBS) * s;
    OBH[s * OST + k] = 0; OBL[s * OST + k] = 0;
  }
  if (tid < 48) LS[tid] = fminf(fmaxf(logstd[tid], -20.f), 2.f);
  __syncthreads();                                      // (1) obs staged

  // ---- enc1: h = tanh(obs @ W1 + b1), K=32, 3-pass split; reads Fb(obs), writes Hb
  {
    f32x4 acc[2][4];
    f32x4 b0 = *(const f32x4*)(eb1 + cb + 4 * h);
    f32x4 b1 = *(const f32x4*)(eb1 + cb + 16 + 4 * h);
#pragma unroll
    for (int nt = 0; nt < 4; ++nt) { acc[0][nt] = b0; acc[1][nt] = b1; }
    bf16x8 aH[2], aL[2], bH[4], bL[4];
#pragma unroll
    for (int ct = 0; ct < 2; ++ct) {
      aH[ct] = *(const bf16x8*)(W1H + (cb + 16 * ct + l15) * 32 + 8 * h);
      aL[ct] = *(const bf16x8*)(W1L + (cb + 16 * ct + l15) * 32 + 8 * h);
    }
#pragma unroll
    for (int nt = 0; nt < 4; ++nt) {
      bH[nt] = *(const bf16x8*)(OBH + (16 * nt + l15) * OST + 8 * h);
      bL[nt] = *(const bf16x8*)(OBL + (16 * nt + l15) * OST + 8 * h);
    }
#pragma unroll
    for (int ct = 0; ct < 2; ++ct)
#pragma unroll
      for (int nt = 0; nt < 4; ++nt) {
        acc[ct][nt] = MFMA(aH[ct], bH[nt], acc[ct][nt]);
        acc[ct][nt] = MFMA(aL[ct], bH[nt], acc[ct][nt]);
        acc[ct][nt] = MFMA(aH[ct], bL[nt], acc[ct][nt]);
      }
    epi_tanh_store(acc, Hb, cb, l15, h);                // Hb disjoint from Fb: no barrier
  }
  __syncthreads();                                      // (2) h visible; obs reads done

  // ---- enc2: feat = tanh(h @ W2 + b2); reads Hb, writes Fb
  {
    f32x4 acc[2][4];
    f32x4 b0 = *(const f32x4*)(eb2 + cb + 4 * h);
    f32x4 b1 = *(const f32x4*)(eb2 + cb + 16 + 4 * h);
#pragma unroll
    for (int nt = 0; nt < 4; ++nt) { acc[0][nt] = b0; acc[1][nt] = b1; }
    gemm256<2>(W2T, Hb, cb, l15, h, acc);
    epi_tanh_store(acc, Fb, cb, l15, h);
  }
  __syncthreads();                                      // (3) feat visible; Hb reads done

  // ---- heads (waves 0-3: read Fb, write MU/SC) + val1 (all waves: read Fb, write Hb)
  if (wid < 4) {
    f32x4 hacc[1][4];
    f32x4 hb;
    if (wid < 3)      hb = *(const f32x4*)(mub + 16 * wid + 4 * h);
    else if (h < 2)   hb = *(const f32x4*)(g0g + 4 * h);
    else              hb = (f32x4){0.f, 0.f, 0.f, 0.f};
#pragma unroll
    for (int nt = 0; nt < 4; ++nt) hacc[0][nt] = hb;
    gemm256<1>(HDT, Fb, 16 * wid, l15, h, hacc);
    if (wid < 3) {
#pragma unroll
      for (int nt = 0; nt < 4; ++nt) {
        uint2 u;
        u.x = pk2(hacc[0][nt][0], hacc[0][nt][1]);
        u.y = pk2(hacc[0][nt][2], hacc[0][nt][3]);
        *(uint2*)(MU + (16 * nt + l15) * MUST + 16 * wid + 4 * h) = u;
      }
    } else if (h < 2) {
#pragma unroll
      for (int nt = 0; nt < 4; ++nt)
        *(f32x4*)(SC + (16 * nt + l15) * SCST + 4 * h) = hacc[0][nt];
    }
  }
  {
    f32x4 acc[2][4];
    f32x4 b0 = *(const f32x4*)(vb1 + cb + 4 * h);
    f32x4 b1 = *(const f32x4*)(vb1 + cb + 16 + 4 * h);
#pragma unroll
    for (int nt = 0; nt < 4; ++nt) { acc[0][nt] = b0; acc[1][nt] = b1; }
    gemm256<2>(V1T, Fb, cb, l15, h, acc);
    epi_tanh_store(acc, Hb, cb, l15, h);                // Hb free since (3)
  }
  __syncthreads();                                      // (4) v1/MU/SC visible

  // ---- val2 + fused v = v2 @ W3 reduction; reads Hb, writes VP
  {
    f32x4 acc[2][4];
    f32x4 b0 = *(const f32x4*)(vb2 + cb + 4 * h);
    f32x4 b1 = *(const f32x4*)(vb2 + cb + 16 + 4 * h);
#pragma unroll
    for (int nt = 0; nt < 4; ++nt) { acc[0][nt] = b0; acc[1][nt] = b1; }
    gemm256<2>(V2T, Hb, cb, l15, h, acc);
    f32x4 w30 = *(const f32x4*)(vW3 + cb + 4 * h);
    f32x4 w31 = *(const f32x4*)(vW3 + cb + 16 + 4 * h);
#pragma unroll
    for (int nt = 0; nt < 4; ++nt) {
      float v = 0.f;
#pragma unroll
      for (int r = 0; r < 4; ++r) {
        v = fmaf(tanh_fast2(acc[0][nt][r]), w30[r], v);
        v = fmaf(tanh_fast2(acc[1][nt][r]), w31[r], v);
      }
      v += __shfl_xor(v, 16);
      v += __shfl_xor(v, 32);
      if (h == 0) VP[wid * TS + 16 * nt + l15] = v;
    }
  }
  __syncthreads();                                      // (5) VP ready

  // ---- final: argmin + near-tie flag + gather (wave 0; lane = sample)
  if (wid == 0) {
    int s = lane;
    int best = 0;
    float bs = SC[s * SCST], bs2 = 3.4e38f;
#pragma unroll
    for (int m = 1; m < NM; ++m) {
      float sm = SC[s * SCST + m];
      if (sm < bs) { bs2 = bs; bs = sm; best = m; }  // strict <: first min on tie
      else if (sm < bs2) bs2 = sm;
    }
    if (cnt && (bs2 - bs) < EPS_MARGIN) {
      int idx = atomicAdd(cnt, 1);
      if (idx < cap) flags[idx] = s0 + s;
    }
    float v = vb3[0];
#pragma unroll
    for (int w = 0; w < NW; ++w) v += VP[w * TS + s];
    float* orow = out + (size_t)(s0 + s) * NOUT;
#pragma unroll
    for (int a = 0; a < NACT; ++a) orow[a] = bf2f(MU[s * MUST + best * NACT + a]);
#pragma unroll
    for (int a = 0; a < NACT; ++a) orow[NACT + a] = LS[best * NACT + a];
    orow[2 * NACT] = v;
  }
}

// ---------------- Pass B: fp64 recheck (verified round-3/6 math; serial enc2 loop) ----------------
extern "C" __global__ __launch_bounds__(256, 2)
void ppo_recheck(const float* __restrict__ obs,
                 const float* __restrict__ eW1, const float* __restrict__ eb1,
                 const float* __restrict__ eW2, const float* __restrict__ eb2,
                 const float* __restrict__ muW, const float* __restrict__ mub,
                 const float* __restrict__ logstd,
                 const float* __restrict__ cen, const float* __restrict__ smean,
                 const float* __restrict__ svar,
                 float* __restrict__ out,
                 const int* cnt, const int* flags, int cap)
{
  if (!cnt) return;
  __shared__ double hbuf[HID];
  __shared__ double fbuf[HID];
  __shared__ double d2buf[NM];
  __shared__ double obsd[NOBS];
  __shared__ int bestv;
  const int tid = threadIdx.x;
  const int n = min(cnt[0], cap);

  for (int i = blockIdx.x; i < n; i += gridDim.x) {
    const int s = flags[i];
    if (tid < NOBS) obsd[tid] = (double)obs[(size_t)s * NOBS + tid];
    __syncthreads();
    double a1 = (double)eb1[tid];
    for (int k = 0; k < NOBS; ++k) a1 = fma(obsd[k], (double)eW1[k * HID + tid], a1);
    hbuf[tid] = tanh(a1);
    __syncthreads();
    double a2 = (double)eb2[tid];
    for (int k = 0; k < HID; ++k) a2 = fma(hbuf[k], (double)eW2[k * HID + tid], a2);
    fbuf[tid] = tanh(a2);
    __syncthreads();
    {
      int g = tid >> 5, l = tid & 31;
      double dot = 0.0, zn = 0.0, cn = 0.0;
      for (int j = 0; j < HID / 32; ++j) {
        int k = l + j * 32;
        double zs = 1.0 / sqrt((double)svar[k] + 1e-6);
        double zw = (fbuf[k] - (double)smean[k]) * zs;
        double ck = (double)cen[g * HID + k];
        dot = fma(zw, ck, dot);
        zn  = fma(zw, zw, zn);
        cn  = fma(ck, ck, cn);
      }
      for (int m = 16; m >= 1; m >>= 1) {
        dot += __shfl_xor(dot, m, 32);
        zn  += __shfl_xor(zn,  m, 32);
        cn  += __shfl_xor(cn,  m, 32);
      }
      if (l == 0) d2buf[g] = zn - 2.0 * dot + cn;
    }
    __syncthreads();
    if (tid == 0) {
      int best = 0;
      double bs = d2buf[0];
      for (int m = 1; m < NM; ++m)
        if (d2buf[m] < bs) { bs = d2buf[m]; best = m; }
      bestv = best;
    }
    __syncthreads();
    const int best = bestv;
    if (tid < NACT) {
      float acc = mub[best * NACT + tid];
      for (int k = 0; k < HID; ++k)
        acc = fmaf((float)fbuf[k], muW[(best * HID + k) * NACT + tid], acc);
      out[(size_t)s * NOUT + tid] = acc;
    } else if (tid < 2 * NACT) {
      int a = tid - NACT;
      float ls = logstd[best * NACT + a];
      out[(size_t)s * NOUT + NACT + a] = fminf(fmaxf(ls, -20.0f), 2.0f);
    }
    __syncthreads();
  }
}

// ---------------- fallback (verified round-3 fp32 path; unused when ws is big) ----------------
extern "C" __global__ __launch_bounds__(NT, 4)
void ppo_fp32_fb(const float* __restrict__ obs,
                 const float* __restrict__ eW1, const float* __restrict__ eb1,
                 const float* __restrict__ eW2, const float* __restrict__ eb2,
                 const float* __restrict__ muW, const float* __restrict__ mub,
                 const float* __restrict__ logstd,
                 const float* __restrict__ vW1, const float* __restrict__ vb1,
                 const float* __restrict__ vW2, const float* __restrict__ vb2,
                 const float* __restrict__ vW3, const float* __restrict__ vb3,
                 const float* __restrict__ cen, const float* __restrict__ smean,
                 const float* __restrict__ svar,
                 float* __restrict__ out, int* cnt, int* flags, int cap)
{
  __shared__ float act[HID * TS];
  __shared__ float mubuf[NM * TS * NACT];
  __shared__ float scbuf[NM * TS];
  __shared__ float zsbuf[HID];
  const int tid  = threadIdx.x;
  const int lane = tid & 63;
  const int wid  = tid >> 6;
  const int c0   = wid * 32;
  const int s0   = blockIdx.x * TS;
  float* obs_s = mubuf;
  for (int idx = tid; idx < TS * NOBS; idx += NT) {
    int s = idx / NOBS, i = idx - s * NOBS;
    obs_s[i * TS + s] = obs[s0 * NOBS + idx];
  }
  if (tid < HID) zsbuf[tid] = (float)(1.0 / sqrt((double)svar[tid] + 1e-6));
  __syncthreads();
  {
    float acc[32];
#pragma unroll
    for (int c = 0; c < 32; ++c) acc[c] = eb1[c0 + c];
    float ob[NOBS];
#pragma unroll
    for (int i = 0; i < NOBS; ++i) ob[i] = obs_s[i * TS + lane];
#pragma unroll
    for (int i = 0; i < NOBS; ++i) {
      const float* w = &eW1[i * HID + c0];
#pragma unroll
      for (int c = 0; c < 32; ++c) acc[c] = fmaf(ob[i], w[c], acc[c]);
    }
#pragma unroll
    for (int c = 0; c < 32; ++c) act[(c0 + c) * TS + lane] = tanh_fast2(acc[c]);
  }
  __syncthreads();
  {
    float acc[32];
#pragma unroll
    for (int c = 0; c < 32; ++c) acc[c] = eb2[c0 + c];
#pragma unroll 4
    for (int k = 0; k < HID; ++k) {
      float a = act[k * TS + lane];
      const float* w = &eW2[k * HID + c0];
#pragma unroll
      for (int c = 0; c < 32; ++c) acc[c] = fmaf(a, w[c], acc[c]);
    }
    __syncthreads();
#pragma unroll
    for (int c = 0; c < 32; ++c) act[(c0 + c) * TS + lane] = tanh_fast2(acc[c]);
  }
  __syncthreads();
  {
    double dot = 0.0, zn = 0.0, cn = 0.0;
    float mu[NACT];
#pragma unroll
    for (int a = 0; a < NACT; ++a) mu[a] = mub[wid * NACT + a];
#pragma unroll 2
    for (int k = 0; k < HID; ++k) {
      float f = act[k * TS + lane];
      double zw = ((double)f - (double)smean[k]) * (double)zsbuf[k];
      double ck = (double)cen[wid * HID + k];
      dot = fma(zw, ck, dot); zn = fma(zw, zw, zn); cn = fma(ck, ck, cn);
      const float* w = &muW[(wid * HID + k) * NACT];
#pragma unroll
      for (int a = 0; a < NACT; ++a) mu[a] = fmaf(f, w[a], mu[a]);
    }
    scbuf[wid * TS + lane] = (float)(zn - 2.0 * dot + cn);
#pragma unroll
    for (int a = 0; a < NACT; ++a) mubuf[(wid * TS + lane) * NACT + a] = mu[a];
  }
  {
    float acc[32];
#pragma unroll
    for (int c = 0; c < 32; ++c) acc[c] = vb1[c0 + c];
#pragma unroll 4
    for (int k = 0; k < HID; ++k) {
      float f = act[k * TS + lane];
      const float* w = &vW1[k * HID + c0];
#pragma unroll
      for (int c = 0; c < 32; ++c) acc[c] = fmaf(f, w[c], acc[c]);
    }
    __syncthreads();
#pragma unroll
    for (int c = 0; c < 32; ++c) act[(c0 + c) * TS + lane] = tanh_fast2(acc[c]);
  }
  __syncthreads();
  {
    float acc[32];
#pragma unroll
    for (int c = 0; c < 32; ++c) acc[c] = vb2[c0 + c];
#pragma unroll 4
    for (int k = 0; k < HID; ++k) {
      float f = act[k * TS + lane];
      const float* w = &vW2[k * HID + c0];
#pragma unroll
      for (int c = 0; c < 32; ++c) acc[c] = fmaf(f, w[c], acc[c]);
    }
    __syncthreads();
#pragma unroll
    for (int c = 0; c < 32; ++c) act[(c0 + c) * TS + lane] = tanh_fast2(acc[c]);
  }
  __syncthreads();
  if (wid == 0) {
    int best = 0;
    float bs = scbuf[lane], bs2 = 3.4e38f;
#pragma unroll
    for (int m = 1; m < NM; ++m) {
      float sm = scbuf[m * TS + lane];
      if (sm < bs) { bs2 = bs; bs = sm; best = m; }
      else if (sm < bs2) bs2 = sm;
    }
    if (cnt && (bs2 - bs) < 1e-2f) {
      int idx = atomicAdd(cnt, 1);
      if (idx < cap) flags[idx] = s0 + lane;
    }
    float v = vb3[0];
#pragma unroll 4
    for (int k = 0; k < HID; ++k) v = fmaf(act[k * TS + lane], vW3[k], v);
    float* orow = &out[(size_t)(s0 + lane) * NOUT];
#pragma unroll
    for (int a = 0; a < NACT; ++a) orow[a] = mubuf[(best * TS + lane) * NACT + a];
#pragma unroll
    for (int a = 0; a < NACT; ++a) {
      float ls = logstd[best * NACT + a];
      orow[NACT + a] = fminf(fmaxf(ls, -20.0f), 2.0f);
    }
    orow[2 * NACT] = v;
  }
}

extern "C" void kernel_launch(void* const* d_in, const int* in_sizes, int n_in,
                              void* d_out, int out_size, void* d_ws, size_t ws_size,
                              hipStream_t stream) {
  const float* obs   = (const float*)d_in[0];
  const float* eW1   = (const float*)d_in[1];
  const float* eb1   = (const float*)d_in[2];
  const float* eW2   = (const float*)d_in[3];
  const float* eb2   = (const float*)d_in[4];
  const float* muW   = (const float*)d_in[5];
  const float* mub   = (const float*)d_in[6];
  const float* lstd  = (const float*)d_in[7];
  const float* vW1   = (const float*)d_in[8];
  const float* vb1   = (const float*)d_in[9];
  const float* vW2   = (const float*)d_in[10];
  const float* vb2   = (const float*)d_in[11];
  const float* vW3   = (const float*)d_in[12];
  const float* vb3   = (const float*)d_in[13];
  const float* cen   = (const float*)d_in[14];
  const float* smean = (const float*)d_in[15];
  const float* svar  = (const float*)d_in[16];
  float* out = (float*)d_out;
  unsigned char* wsb = (unsigned char*)d_ws;

  if (ws_size >= (size_t)WS_NEED) {
    int* cnt = (int*)wsb;
    int* flags = (int*)(wsb + OFF_FLAGS);
    hipLaunchKernelGGL(ppo_prep, dim3(865), dim3(256), 0, stream,
                       eW1, eW2, vW1, vW2, muW, cen, smean, svar, wsb, cnt);
    hipLaunchKernelGGL(ppo_mfma, dim3(B_TOT / TS), dim3(NT), 0, stream,
                       obs, eb1, eb2, mub, lstd, vb1, vb2, vW3, vb3,
                       (const unsigned char*)wsb, out, cnt, flags, CAPF);
    hipLaunchKernelGGL(ppo_recheck, dim3(4096), dim3(256), 0, stream,
                       obs, eW1, eb1, eW2, eb2, muW, mub, lstd,
                       cen, smean, svar, out, cnt, flags, CAPF);
  } else {
    int* cnt = nullptr; int* flags = nullptr; int cap = 0;
    if (ws_size >= 1024) {
      cnt = (int*)wsb;
      flags = cnt + 16;
      size_t c = (ws_size - 64) / 4;
      cap = (int)(c < (size_t)CAPF ? c : (size_t)CAPF);
    }
    hipLaunchKernelGGL(ppo_zero, dim3(1), dim3(64), 0, stream, cnt);
    hipLaunchKernelGGL(ppo_fp32_fb, dim3(B_TOT / TS), dim3(NT), 0, stream,
                       obs, eW1, eb1, eW2, eb2, muW, mub, lstd,
                       vW1, vb1, vW2, vb2, vW3, vb3, cen, smean, svar, out,
                       cnt, flags, cap);
    hipLaunchKernelGGL(ppo_recheck, dim3(4096), dim3(256), 0, stream,
                       obs, eW1, eb1, eW2, eb2, muW, mub, lstd,
                       cen, smean, svar, out, cnt, flags, cap);
  }
}

// Round 13
// 227.537 us; speedup vs baseline: 1.6281x; 1.0027x over previous
//
#include <hip/hip_runtime.h>
#include <math.h>

typedef __attribute__((ext_vector_type(8))) short bf16x8;
typedef __attribute__((ext_vector_type(4))) float f32x4;

#define B_TOT 131072
#define NOBS 17
#define NACT 6
#define NM 8
#define HID 256
#define TS 64
#define NT 512
#define NW 8
#define NOUT 13
#define EPS_MARGIN 0.20f   // 10-sigma of score-diff error (bf16 feat+G + single-pass enc2)
#define CAPF 65536

// LDS row strides (elements)
#define AST 264
#define OST 40
#define MUST 52
#define SCST 12

// ---- workspace layout (bytes) ----
#define OFF_FLAGS 64
#define OFF_W1H  (OFF_FLAGS + 4*CAPF)       /* [256][32] bf16 hi */
#define OFF_W1L  (OFF_W1H + 256*32*2)
#define OFF_W2T  (OFF_W1L + 256*32*2)       /* [256][256] bf16, transposed */
#define OFF_V1T  (OFF_W2T + 256*256*2)
#define OFF_V2T  (OFF_V1T + 256*256*2)
#define OFF_HDT  (OFF_V2T + 256*256*2)      /* [64][256]: 48 mu cols | 8 G cols | 8 pad */
#define OFF_G0   (OFF_HDT + 64*256*2)
#define WS_NEED  (OFF_G0 + 64)

__device__ __forceinline__ unsigned short f2bf(float f) {  // RNE
  unsigned int u = __float_as_uint(f);
  u = (u + 0x7fffu + ((u >> 16) & 1u)) >> 16;
  return (unsigned short)u;
}
__device__ __forceinline__ float bf2f(unsigned short h) {
  return __uint_as_float(((unsigned int)h) << 16);
}
__device__ __forceinline__ float tanh_fast2(float x) {
  float e = __expf(2.0f * x);
  float r = __builtin_amdgcn_rcpf(e + 1.0f);
  return 1.0f - 2.0f * r;
}
__device__ __forceinline__ unsigned int pk2(float a, float b) {  // lo16=bf(a), hi16=bf(b)
  unsigned int r;
  asm("v_cvt_pk_bf16_f32 %0, %1, %2" : "=v"(r) : "v"(a), "v"(b));
  return r;
}
__device__ __forceinline__ f32x4 MFMA(bf16x8 a, bf16x8 b, f32x4 c) {
  return __builtin_amdgcn_mfma_f32_16x16x32_bf16(a, b, c, 0, 0, 0);
}

extern "C" __global__ void ppo_zero(int* cnt) {
  if (cnt && threadIdx.x == 0) cnt[0] = 0;
}

// ---------------- prep v2: COALESCED tile transpose + head matrix + g0 + cnt=0 ----------------
// r12 prep gave each block ONE weight column: 256 scattered 4B reads (stride 1KB) per block.
// v2: blocks 0-47 do 64x64 LDS tile transposes with coalesced 256B reads / 128B writes.
// Grid: 48 transpose + 64 HDT + 32 W1 + 1 g0 = 145 blocks.
extern "C" __global__ __launch_bounds__(256)
void ppo_prep(const float* __restrict__ eW1, const float* __restrict__ eW2,
              const float* __restrict__ vW1, const float* __restrict__ vW2,
              const float* __restrict__ muW, const float* __restrict__ cen,
              const float* __restrict__ smean, const float* __restrict__ svar,
              unsigned char* wsb, int* cnt)
{
  const int b = blockIdx.x, tid = threadIdx.x;
  if (b < 48) {                          // 64x64 tile transpose, f32 -> bf16
    __shared__ unsigned short tile[64][65];   // [c_local][k_local], +1 pad
    const int mat = b >> 4, t6 = b & 15;
    const float* src = (mat == 0) ? eW2 : (mat == 1) ? vW1 : vW2;
    unsigned short* dst = (unsigned short*)(wsb + ((mat == 0) ? OFF_W2T : (mat == 1) ? OFF_V1T : OFF_V2T));
    const int k0 = (t6 >> 2) * 64, c0 = (t6 & 3) * 64;
    const int cl = tid & 63, rq = tid >> 6;      // 4 rows per pass
#pragma unroll
    for (int i = 0; i < 64; i += 4) {
      int k = k0 + i + rq;
      tile[cl][i + rq] = f2bf(src[k * 256 + c0 + cl]);  // coalesced read (cl contiguous)
    }
    __syncthreads();
#pragma unroll
    for (int i = 0; i < 64; i += 4) {
      int c = c0 + i + rq;
      dst[c * 256 + k0 + cl] = tile[i + rq][cl];        // coalesced write (cl contiguous)
    }
    return;
  }
  if (b < 112) {                         // HDT: mu cols 0-47, G cols 48-55, pad 56-63
    int u = (b - 48) * 256 + tid;        // [0, 16384)
    int c = u >> 8, k = u & 255;
    float v = 0.f;
    if (c < 48) { int m = c / 6, a = c - 6 * m; v = muW[(m * 256 + k) * 6 + a]; }
    else if (c < 56) {
      int m = c - 48;
      double s = 1.0 / sqrt((double)svar[k] + 1e-6);
      v = (float)(-2.0 * s * (double)cen[m * 256 + k]);
    }
    ((unsigned short*)(wsb + OFF_HDT))[c * 256 + k] = f2bf(v);
    return;
  }
  if (b < 144) {                         // W1T hi/lo, K padded 17->32
    int u = (b - 112) * 256 + tid;       // [0, 8192)
    int c = u >> 5, k = u & 31;
    float v = (k < NOBS) ? eW1[k * 256 + c] : 0.f;
    unsigned short hi = f2bf(v);
    ((unsigned short*)(wsb + OFF_W1H))[c * 32 + k] = hi;
    ((unsigned short*)(wsb + OFF_W1L))[c * 32 + k] = f2bf(v - bf2f(hi));
    return;
  }
  {                                      // b == 144: g0 + cnt=0
    int m = tid >> 5, l = tid & 31;
    double acc = 0.0;
    for (int k = l; k < HID; k += 32) {
      double s = 1.0 / sqrt((double)svar[k] + 1e-6);
      double c = (double)cen[m * HID + k];
      acc += c * (2.0 * (double)smean[k] * s + c);
    }
#pragma unroll
    for (int w = 16; w >= 1; w >>= 1) acc += __shfl_xor(acc, w, 32);
    if (l == 0) ((float*)(wsb + OFF_G0))[m] = (float)acc;
    if (tid == 0) cnt[0] = 0;
  }
}

// ---- K=256 single-pass gemm: A = weights (global, transposed), B = activations (LDS)
template<int CT>
__device__ __forceinline__ void gemm256(const unsigned short* __restrict__ WT,
                                        const unsigned short* act,
                                        int cb, int l15, int h, f32x4 acc[CT][4])
{
#pragma unroll
  for (int kt = 0; kt < 8; ++kt) {
    int kk = kt * 32 + 8 * h;
    bf16x8 a[CT], b[4];
#pragma unroll
    for (int ct = 0; ct < CT; ++ct)
      a[ct] = *(const bf16x8*)(WT + (cb + 16 * ct + l15) * 256 + kk);
#pragma unroll
    for (int nt = 0; nt < 4; ++nt)
      b[nt] = *(const bf16x8*)(act + (16 * nt + l15) * AST + kk);
#pragma unroll
    for (int ct = 0; ct < CT; ++ct)
#pragma unroll
      for (int nt = 0; nt < 4; ++nt)
        acc[ct][nt] = MFMA(a[ct], b[nt], acc[ct][nt]);
  }
}

// epilogue: tanh -> bf16 -> one b64 write per tile
__device__ __forceinline__ void epi_tanh_store(f32x4 acc[2][4], unsigned short* dst,
                                               int cb, int l15, int h)
{
#pragma unroll
  for (int ct = 0; ct < 2; ++ct)
#pragma unroll
    for (int nt = 0; nt < 4; ++nt) {
      float t0 = tanh_fast2(acc[ct][nt][0]);
      float t1 = tanh_fast2(acc[ct][nt][1]);
      float t2 = tanh_fast2(acc[ct][nt][2]);
      float t3 = tanh_fast2(acc[ct][nt][3]);
      uint2 u; u.x = pk2(t0, t1); u.y = pk2(t2, t3);
      *(uint2*)(dst + (16 * nt + l15) * AST + cb + 16 * ct + 4 * h) = u;
    }
}

// ---------------- main fused kernel: ROUND-6 BYTE-EXACT (proven ~135-141 us, no spill) ----------------
// Do NOT graft onto this kernel: r8 launch_bounds(,6) -> 432 MB spill; r10 cross-phase
// fragment hoist -> 45 MB spill; r11 in-kernel fp64 tail -> whole-kernel codegen collapse.
extern "C" __global__ __launch_bounds__(NT, 4)
void ppo_mfma(const float* __restrict__ obs,
              const float* __restrict__ eb1, const float* __restrict__ eb2,
              const float* __restrict__ mub, const float* __restrict__ logstd,
              const float* __restrict__ vb1, const float* __restrict__ vb2,
              const float* __restrict__ vW3, const float* __restrict__ vb3,
              const unsigned char* __restrict__ wsb,
              float* __restrict__ out, int* cnt, int* flags, int cap)
{
  __shared__ unsigned short Hb[TS * AST];   // 33792 B: h, then v1
  __shared__ unsigned short Fb[TS * AST];   // 33792 B: feat (front aliased by obs staging)
  __shared__ unsigned short MU[TS * MUST];  // 6656 B
  __shared__ float SC[TS * SCST];           // 3072 B
  __shared__ float VP[NW * TS];             // 2048 B
  __shared__ float LS[48];                  // total 79552 B -> 2 blocks/CU

  const int tid = threadIdx.x, lane = tid & 63, wid = tid >> 6;
  const int l15 = lane & 15, h = lane >> 4;
  const int cb = wid * 32;
  const int s0 = blockIdx.x * TS;

  const unsigned short* W1H = (const unsigned short*)(wsb + OFF_W1H);
  const unsigned short* W1L = (const unsigned short*)(wsb + OFF_W1L);
  const unsigned short* W2T = (const unsigned short*)(wsb + OFF_W2T);
  const unsigned short* V1T = (const unsigned short*)(wsb + OFF_V1T);
  const unsigned short* V2T = (const unsigned short*)(wsb + OFF_V2T);
  const unsigned short* HDT = (const unsigned short*)(wsb + OFF_HDT);
  const float* g0g = (const float*)(wsb + OFF_G0);

  unsigned short* OBH = Fb;                 // [64][40] obs hi (alias; dead before Fb written)
  unsigned short* OBL = Fb + TS * OST;      // [64][40] obs lo

  // ---- stage: obs split hi/lo, zero K-pad, logstd clamp
  for (int t = tid; t < TS * NOBS; t += NT) {
    int s = t / NOBS, k = t - NOBS * s;
    float v = obs[(size_t)s0 * NOBS + t];
    unsigned short hi = f2bf(v);
    OBH[s * OST + k] = hi;
    OBL[s * OST + k] = f2bf(v - bf2f(hi));
  }
  for (int t = tid; t < TS * (32 - NOBS); t += NT) {
    int s = t / (32 - NOBS), k = NOBS + t - (32 - NOBS) * s;
    OBH[s * OST + k] = 0; OBL[s * OST + k] = 0;
  }
  if (tid < 48) LS[tid] = fminf(fmaxf(logstd[tid], -20.f), 2.f);
  __syncthreads();                                      // (1) obs staged

  // ---- enc1: h = tanh(obs @ W1 + b1), K=32, 3-pass split; reads Fb(obs), writes Hb
  {
    f32x4 acc[2][4];
    f32x4 b0 = *(const f32x4*)(eb1 + cb + 4 * h);
    f32x4 b1 = *(const f32x4*)(eb1 + cb + 16 + 4 * h);
#pragma unroll
    for (int nt = 0; nt < 4; ++nt) { acc[0][nt] = b0; acc[1][nt] = b1; }
    bf16x8 aH[2], aL[2], bH[4], bL[4];
#pragma unroll
    for (int ct = 0; ct < 2; ++ct) {
      aH[ct] = *(const bf16x8*)(W1H + (cb + 16 * ct + l15) * 32 + 8 * h);
      aL[ct] = *(const bf16x8*)(W1L + (cb + 16 * ct + l15) * 32 + 8 * h);
    }
#pragma unroll
    for (int nt = 0; nt < 4; ++nt) {
      bH[nt] = *(const bf16x8*)(OBH + (16 * nt + l15) * OST + 8 * h);
      bL[nt] = *(const bf16x8*)(OBL + (16 * nt + l15) * OST + 8 * h);
    }
#pragma unroll
    for (int ct = 0; ct < 2; ++ct)
#pragma unroll
      for (int nt = 0; nt < 4; ++nt) {
        acc[ct][nt] = MFMA(aH[ct], bH[nt], acc[ct][nt]);
        acc[ct][nt] = MFMA(aL[ct], bH[nt], acc[ct][nt]);
        acc[ct][nt] = MFMA(aH[ct], bL[nt], acc[ct][nt]);
      }
    epi_tanh_store(acc, Hb, cb, l15, h);                // Hb disjoint from Fb: no barrier
  }
  __syncthreads();                                      // (2) h visible; obs reads done

  // ---- enc2: feat = tanh(h @ W2 + b2); reads Hb, writes Fb
  {
    f32x4 acc[2][4];
    f32x4 b0 = *(const f32x4*)(eb2 + cb + 4 * h);
    f32x4 b1 = *(const f32x4*)(eb2 + cb + 16 + 4 * h);
#pragma unroll
    for (int nt = 0; nt < 4; ++nt) { acc[0][nt] = b0; acc[1][nt] = b1; }
    gemm256<2>(W2T, Hb, cb, l15, h, acc);
    epi_tanh_store(acc, Fb, cb, l15, h);
  }
  __syncthreads();                                      // (3) feat visible; Hb reads done

  // ---- heads (waves 0-3: read Fb, write MU/SC) + val1 (all waves: read Fb, write Hb)
  if (wid < 4) {
    f32x4 hacc[1][4];
    f32x4 hb;
    if (wid < 3)      hb = *(const f32x4*)(mub + 16 * wid + 4 * h);
    else if (h < 2)   hb = *(const f32x4*)(g0g + 4 * h);
    else              hb = (f32x4){0.f, 0.f, 0.f, 0.f};
#pragma unroll
    for (int nt = 0; nt < 4; ++nt) hacc[0][nt] = hb;
    gemm256<1>(HDT, Fb, 16 * wid, l15, h, hacc);
    if (wid < 3) {
#pragma unroll
      for (int nt = 0; nt < 4; ++nt) {
        uint2 u;
        u.x = pk2(hacc[0][nt][0], hacc[0][nt][1]);
        u.y = pk2(hacc[0][nt][2], hacc[0][nt][3]);
        *(uint2*)(MU + (16 * nt + l15) * MUST + 16 * wid + 4 * h) = u;
      }
    } else if (h < 2) {
#pragma unroll
      for (int nt = 0; nt < 4; ++nt)
        *(f32x4*)(SC + (16 * nt + l15) * SCST + 4 * h) = hacc[0][nt];
    }
  }
  {
    f32x4 acc[2][4];
    f32x4 b0 = *(const f32x4*)(vb1 + cb + 4 * h);
    f32x4 b1 = *(const f32x4*)(vb1 + cb + 16 + 4 * h);
#pragma unroll
    for (int nt = 0; nt < 4; ++nt) { acc[0][nt] = b0; acc[1][nt] = b1; }
    gemm256<2>(V1T, Fb, cb, l15, h, acc);
    epi_tanh_store(acc, Hb, cb, l15, h);                // Hb free since (3)
  }
  __syncthreads();                                      // (4) v1/MU/SC visible

  // ---- val2 + fused v = v2 @ W3 reduction; reads Hb, writes VP
  {
    f32x4 acc[2][4];
    f32x4 b0 = *(const f32x4*)(vb2 + cb + 4 * h);
    f32x4 b1 = *(const f32x4*)(vb2 + cb + 16 + 4 * h);
#pragma unroll
    for (int nt = 0; nt < 4; ++nt) { acc[0][nt] = b0; acc[1][nt] = b1; }
    gemm256<2>(V2T, Hb, cb, l15, h, acc);
    f32x4 w30 = *(const f32x4*)(vW3 + cb + 4 * h);
    f32x4 w31 = *(const f32x4*)(vW3 + cb + 16 + 4 * h);
#pragma unroll
    for (int nt = 0; nt < 4; ++nt) {
      float v = 0.f;
#pragma unroll
      for (int r = 0; r < 4; ++r) {
        v = fmaf(tanh_fast2(acc[0][nt][r]), w30[r], v);
        v = fmaf(tanh_fast2(acc[1][nt][r]), w31[r], v);
      }
      v += __shfl_xor(v, 16);
      v += __shfl_xor(v, 32);
      if (h == 0) VP[wid * TS + 16 * nt + l15] = v;
    }
  }
  __syncthreads();                                      // (5) VP ready

  // ---- final: argmin + near-tie flag + gather (wave 0; lane = sample)
  if (wid == 0) {
    int s = lane;
    int best = 0;
    float bs = SC[s * SCST], bs2 = 3.4e38f;
#pragma unroll
    for (int m = 1; m < NM; ++m) {
      float sm = SC[s * SCST + m];
      if (sm < bs) { bs2 = bs; bs = sm; best = m; }  // strict <: first min on tie
      else if (sm < bs2) bs2 = sm;
    }
    if (cnt && (bs2 - bs) < EPS_MARGIN) {
      int idx = atomicAdd(cnt, 1);
      if (idx < cap) flags[idx] = s0 + s;
    }
    float v = vb3[0];
#pragma unroll
    for (int w = 0; w < NW; ++w) v += VP[w * TS + s];
    float* orow = out + (size_t)(s0 + s) * NOUT;
#pragma unroll
    for (int a = 0; a < NACT; ++a) orow[a] = bf2f(MU[s * MUST + best * NACT + a]);
#pragma unroll
    for (int a = 0; a < NACT; ++a) orow[NACT + a] = LS[best * NACT + a];
    orow[2 * NACT] = v;
  }
}

// ---------------- Pass B: fp64 recheck (verified round-3/6 math; serial enc2 loop) ----------------
extern "C" __global__ __launch_bounds__(256, 2)
void ppo_recheck(const float* __restrict__ obs,
                 const float* __restrict__ eW1, const float* __restrict__ eb1,
                 const float* __restrict__ eW2, const float* __restrict__ eb2,
                 const float* __restrict__ muW, const float* __restrict__ mub,
                 const float* __restrict__ logstd,
                 const float* __restrict__ cen, const float* __restrict__ smean,
                 const float* __restrict__ svar,
                 float* __restrict__ out,
                 const int* cnt, const int* flags, int cap)
{
  if (!cnt) return;
  __shared__ double hbuf[HID];
  __shared__ double fbuf[HID];
  __shared__ double d2buf[NM];
  __shared__ double obsd[NOBS];
  __shared__ int bestv;
  const int tid = threadIdx.x;
  const int n = min(cnt[0], cap);

  for (int i = blockIdx.x; i < n; i += gridDim.x) {
    const int s = flags[i];
    if (tid < NOBS) obsd[tid] = (double)obs[(size_t)s * NOBS + tid];
    __syncthreads();
    double a1 = (double)eb1[tid];
    for (int k = 0; k < NOBS; ++k) a1 = fma(obsd[k], (double)eW1[k * HID + tid], a1);
    hbuf[tid] = tanh(a1);
    __syncthreads();
    double a2 = (double)eb2[tid];
    for (int k = 0; k < HID; ++k) a2 = fma(hbuf[k], (double)eW2[k * HID + tid], a2);
    fbuf[tid] = tanh(a2);
    __syncthreads();
    {
      int g = tid >> 5, l = tid & 31;
      double dot = 0.0, zn = 0.0, cn = 0.0;
      for (int j = 0; j < HID / 32; ++j) {
        int k = l + j * 32;
        double zs = 1.0 / sqrt((double)svar[k] + 1e-6);
        double zw = (fbuf[k] - (double)smean[k]) * zs;
        double ck = (double)cen[g * HID + k];
        dot = fma(zw, ck, dot);
        zn  = fma(zw, zw, zn);
        cn  = fma(ck, ck, cn);
      }
      for (int m = 16; m >= 1; m >>= 1) {
        dot += __shfl_xor(dot, m, 32);
        zn  += __shfl_xor(zn,  m, 32);
        cn  += __shfl_xor(cn,  m, 32);
      }
      if (l == 0) d2buf[g] = zn - 2.0 * dot + cn;
    }
    __syncthreads();
    if (tid == 0) {
      int best = 0;
      double bs = d2buf[0];
      for (int m = 1; m < NM; ++m)
        if (d2buf[m] < bs) { bs = d2buf[m]; best = m; }
      bestv = best;
    }
    __syncthreads();
    const int best = bestv;
    if (tid < NACT) {
      float acc = mub[best * NACT + tid];
      for (int k = 0; k < HID; ++k)
        acc = fmaf((float)fbuf[k], muW[(best * HID + k) * NACT + tid], acc);
      out[(size_t)s * NOUT + tid] = acc;
    } else if (tid < 2 * NACT) {
      int a = tid - NACT;
      float ls = logstd[best * NACT + a];
      out[(size_t)s * NOUT + NACT + a] = fminf(fmaxf(ls, -20.0f), 2.0f);
    }
    __syncthreads();
  }
}

// ---------------- fallback (verified round-3 fp32 path; unused when ws is big) ----------------
extern "C" __global__ __launch_bounds__(NT, 4)
void ppo_fp32_fb(const float* __restrict__ obs,
                 const float* __restrict__ eW1, const float* __restrict__ eb1,
                 const float* __restrict__ eW2, const float* __restrict__ eb2,
                 const float* __restrict__ muW, const float* __restrict__ mub,
                 const float* __restrict__ logstd,
                 const float* __restrict__ vW1, const float* __restrict__ vb1,
                 const float* __restrict__ vW2, const float* __restrict__ vb2,
                 const float* __restrict__ vW3, const float* __restrict__ vb3,
                 const float* __restrict__ cen, const float* __restrict__ smean,
                 const float* __restrict__ svar,
                 float* __restrict__ out, int* cnt, int* flags, int cap)
{
  __shared__ float act[HID * TS];
  __shared__ float mubuf[NM * TS * NACT];
  __shared__ float scbuf[NM * TS];
  __shared__ float zsbuf[HID];
  const int tid  = threadIdx.x;
  const int lane = tid & 63;
  const int wid  = tid >> 6;
  const int c0   = wid * 32;
  const int s0   = blockIdx.x * TS;
  float* obs_s = mubuf;
  for (int idx = tid; idx < TS * NOBS; idx += NT) {
    int s = idx / NOBS, i = idx - s * NOBS;
    obs_s[i * TS + s] = obs[s0 * NOBS + idx];
  }
  if (tid < HID) zsbuf[tid] = (float)(1.0 / sqrt((double)svar[tid] + 1e-6));
  __syncthreads();
  {
    float acc[32];
#pragma unroll
    for (int c = 0; c < 32; ++c) acc[c] = eb1[c0 + c];
    float ob[NOBS];
#pragma unroll
    for (int i = 0; i < NOBS; ++i) ob[i] = obs_s[i * TS + lane];
#pragma unroll
    for (int i = 0; i < NOBS; ++i) {
      const float* w = &eW1[i * HID + c0];
#pragma unroll
      for (int c = 0; c < 32; ++c) acc[c] = fmaf(ob[i], w[c], acc[c]);
    }
#pragma unroll
    for (int c = 0; c < 32; ++c) act[(c0 + c) * TS + lane] = tanh_fast2(acc[c]);
  }
  __syncthreads();
  {
    float acc[32];
#pragma unroll
    for (int c = 0; c < 32; ++c) acc[c] = eb2[c0 + c];
#pragma unroll 4
    for (int k = 0; k < HID; ++k) {
      float a = act[k * TS + lane];
      const float* w = &eW2[k * HID + c0];
#pragma unroll
      for (int c = 0; c < 32; ++c) acc[c] = fmaf(a, w[c], acc[c]);
    }
    __syncthreads();
#pragma unroll
    for (int c = 0; c < 32; ++c) act[(c0 + c) * TS + lane] = tanh_fast2(acc[c]);
  }
  __syncthreads();
  {
    double dot = 0.0, zn = 0.0, cn = 0.0;
    float mu[NACT];
#pragma unroll
    for (int a = 0; a < NACT; ++a) mu[a] = mub[wid * NACT + a];
#pragma unroll 2
    for (int k = 0; k < HID; ++k) {
      float f = act[k * TS + lane];
      double zw = ((double)f - (double)smean[k]) * (double)zsbuf[k];
      double ck = (double)cen[wid * HID + k];
      dot = fma(zw, ck, dot); zn = fma(zw, zw, zn); cn = fma(ck, ck, cn);
      const float* w = &muW[(wid * HID + k) * NACT];
#pragma unroll
      for (int a = 0; a < NACT; ++a) mu[a] = fmaf(f, w[a], mu[a]);
    }
    scbuf[wid * TS + lane] = (float)(zn - 2.0 * dot + cn);
#pragma unroll
    for (int a = 0; a < NACT; ++a) mubuf[(wid * TS + lane) * NACT + a] = mu[a];
  }
  {
    float acc[32];
#pragma unroll
    for (int c = 0; c < 32; ++c) acc[c] = vb1[c0 + c];
#pragma unroll 4
    for (int k = 0; k < HID; ++k) {
      float f = act[k * TS + lane];
      const float* w = &vW1[k * HID + c0];
#pragma unroll
      for (int c = 0; c < 32; ++c) acc[c] = fmaf(f, w[c], acc[c]);
    }
    __syncthreads();
#pragma unroll
    for (int c = 0; c < 32; ++c) act[(c0 + c) * TS + lane] = tanh_fast2(acc[c]);
  }
  __syncthreads();
  {
    float acc[32];
#pragma unroll
    for (int c = 0; c < 32; ++c) acc[c] = vb2[c0 + c];
#pragma unroll 4
    for (int k = 0; k < HID; ++k) {
      float f = act[k * TS + lane];
      const float* w = &vW2[k * HID + c0];
#pragma unroll
      for (int c = 0; c < 32; ++c) acc[c] = fmaf(f, w[c], acc[c]);
    }
    __syncthreads();
#pragma unroll
    for (int c = 0; c < 32; ++c) act[(c0 + c) * TS + lane] = tanh_fast2(acc[c]);
  }
  __syncthreads();
  if (wid == 0) {
    int best = 0;
    float bs = scbuf[lane], bs2 = 3.4e38f;
#pragma unroll
    for (int m = 1; m < NM; ++m) {
      float sm = scbuf[m * TS + lane];
      if (sm < bs) { bs2 = bs; bs = sm; best = m; }
      else if (sm < bs2) bs2 = sm;
    }
    if (cnt && (bs2 - bs) < 1e-2f) {
      int idx = atomicAdd(cnt, 1);
      if (idx < cap) flags[idx] = s0 + lane;
    }
    float v = vb3[0];
#pragma unroll 4
    for (int k = 0; k < HID; ++k) v = fmaf(act[k * TS + lane], vW3[k], v);
    float* orow = &out[(size_t)(s0 + lane) * NOUT];
#pragma unroll
    for (int a = 0; a < NACT; ++a) orow[a] = mubuf[(best * TS + lane) * NACT + a];
#pragma unroll
    for (int a = 0; a < NACT; ++a) {
      float ls = logstd[best * NACT + a];
      orow[NACT + a] = fminf(fmaxf(ls, -20.0f), 2.0f);
    }
    orow[2 * NACT] = v;
  }
}

extern "C" void kernel_launch(void* const* d_in, const int* in_sizes, int n_in,
                              void* d_out, int out_size, void* d_ws, size_t ws_size,
                              hipStream_t stream) {
  const float* obs   = (const float*)d_in[0];
  const float* eW1   = (const float*)d_in[1];
  const float* eb1   = (const float*)d_in[2];
  const float* eW2   = (const float*)d_in[3];
  const float* eb2   = (const float*)d_in[4];
  const float* muW   = (const float*)d_in[5];
  const float* mub   = (const float*)d_in[6];
  const float* lstd  = (const float*)d_in[7];
  const float* vW1   = (const float*)d_in[8];
  const float* vb1   = (const float*)d_in[9];
  const float* vW2   = (const float*)d_in[10];
  const float* vb2   = (const float*)d_in[11];
  const float* vW3   = (const float*)d_in[12];
  const float* vb3   = (const float*)d_in[13];
  const float* cen   = (const float*)d_in[14];
  const float* smean = (const float*)d_in[15];
  const float* svar  = (const float*)d_in[16];
  float* out = (float*)d_out;
  unsigned char* wsb = (unsigned char*)d_ws;

  if (ws_size >= (size_t)WS_NEED) {
    int* cnt = (int*)wsb;
    int* flags = (int*)(wsb + OFF_FLAGS);
    hipLaunchKernelGGL(ppo_prep, dim3(145), dim3(256), 0, stream,
                       eW1, eW2, vW1, vW2, muW, cen, smean, svar, wsb, cnt);
    hipLaunchKernelGGL(ppo_mfma, dim3(B_TOT / TS), dim3(NT), 0, stream,
                       obs, eb1, eb2, mub, lstd, vb1, vb2, vW3, vb3,
                       (const unsigned char*)wsb, out, cnt, flags, CAPF);
    hipLaunchKernelGGL(ppo_recheck, dim3(4096), dim3(256), 0, stream,
                       obs, eW1, eb1, eW2, eb2, muW, mub, lstd,
                       cen, smean, svar, out, cnt, flags, CAPF);
  } else {
    int* cnt = nullptr; int* flags = nullptr; int cap = 0;
    if (ws_size >= 1024) {
      cnt = (int*)wsb;
      flags = cnt + 16;
      size_t c = (ws_size - 64) / 4;
      cap = (int)(c < (size_t)CAPF ? c : (size_t)CAPF);
    }
    hipLaunchKernelGGL(ppo_zero, dim3(1), dim3(64), 0, stream, cnt);
    hipLaunchKernelGGL(ppo_fp32_fb, dim3(B_TOT / TS), dim3(NT), 0, stream,
                       obs, eW1, eb1, eW2, eb2, muW, mub, lstd,
                       vW1, vb1, vW2, vb2, vW3, vb3, cen, smean, svar, out,
                       cnt, flags, cap);
    hipLaunchKernelGGL(ppo_recheck, dim3(4096), dim3(256), 0, stream,
                       obs, eW1, eb1, eW2, eb2, muW, mub, lstd,
                       cen, smean, svar, out, cnt, flags, cap);
  }
}